// Round 1
// baseline (265.701 us; speedup 1.0000x reference)
//
#include <hip/hip_runtime.h>
#include <math.h>

#define HG 512
#define WG 512
#define NN (HG * WG)
#define F 64
#define SP 76   // padded LDS row stride (floats): 16B-aligned, breaks power-of-2 banks

__device__ __forceinline__ float dinv_of(int r, int c) {
    // deg = 1 (self loop) + neighbor count; exactly 3.0/4.0/5.0 like the reference
    float deg = 1.0f + (float)((r > 0) + (r < HG - 1) + (c > 0) + (c < WG - 1));
    return rsqrtf(deg);
}

// Kernel 1: h1[n][f] = relu( (dinv_i^2 x_i + dinv_i * sum_j dinv_j x_j) @ W1 + b1 )
// One thread per (node, feature). x loads are wave-uniform per node (broadcast, L1-hit).
__global__ __launch_bounds__(256) void k1(const float* __restrict__ x,
                                          const float* __restrict__ W1,
                                          const float* __restrict__ b1,
                                          float* __restrict__ h1) {
    int gid = blockIdx.x * blockDim.x + threadIdx.x;
    int n = gid >> 6;   // node
    int f = gid & 63;   // feature
    int r = n >> 9, c = n & (WG - 1);
    float di = dinv_of(r, c);
    float s0 = di * di * x[2 * n];
    float s1 = di * di * x[2 * n + 1];
    if (c > 0)      { float w = di * dinv_of(r, c - 1); s0 += w * x[2 * (n - 1)];  s1 += w * x[2 * (n - 1) + 1]; }
    if (c < WG - 1) { float w = di * dinv_of(r, c + 1); s0 += w * x[2 * (n + 1)];  s1 += w * x[2 * (n + 1) + 1]; }
    if (r > 0)      { float w = di * dinv_of(r - 1, c); s0 += w * x[2 * (n - WG)]; s1 += w * x[2 * (n - WG) + 1]; }
    if (r < HG - 1) { float w = di * dinv_of(r + 1, c); s0 += w * x[2 * (n + WG)]; s1 += w * x[2 * (n + WG) + 1]; }
    float h = fmaf(s0, W1[f], fmaf(s1, W1[F + f], b1[f]));
    h1[(size_t)n * F + f] = fmaxf(h, 0.0f);
}

// Kernel 2: per 64-node tile (one grid row segment; 64 | 512 so row is uniform):
//   S[m][k] = stencil(h1)   (LDS)
//   C[m][f] = S @ W2        (register-blocked 4x4 per thread, W2^T staged in LDS)
//   out[m]  = sigmoid( sum_f relu(C[m][f] + b2[f]) * Wfc[f] + bfc )
__global__ __launch_bounds__(256) void k2(const float* __restrict__ h1,
                                          const float* __restrict__ W2,
                                          const float* __restrict__ b2,
                                          const float* __restrict__ Wfc,
                                          const float* __restrict__ bfc,
                                          float* __restrict__ out) {
    __shared__ float S[64 * SP];    // S[m][k], stride SP
    __shared__ float BT[64 * SP];   // BT[f][k] = W2[k][f]
    __shared__ float P[64 * 17];    // fc partials, padded stride 17

    int tid = threadIdx.x;
    int n0 = blockIdx.x * 64;
    int r = n0 >> 9;                // whole tile lies in one grid row

    // stage W2 transposed into LDS (one-time, 16 KB)
    for (int i = tid; i < 64 * 64; i += 256) {
        int k = i >> 6, f = i & 63;
        BT[f * SP + k] = W2[i];
    }

    // phase 1: stencil-gather S. thread (m0 = tid/64, f = tid%64), 16 nodes each.
    int f = tid & 63;
    int m0 = tid >> 6;
    for (int mm = m0; mm < 64; mm += 4) {
        int n = n0 + mm;
        int c = n & (WG - 1);
        float di = dinv_of(r, c);
        float acc = di * di * h1[(size_t)n * F + f];
        if (c > 0)      acc += di * dinv_of(r, c - 1) * h1[(size_t)(n - 1) * F + f];
        if (c < WG - 1) acc += di * dinv_of(r, c + 1) * h1[(size_t)(n + 1) * F + f];
        if (r > 0)      acc += di * dinv_of(r - 1, c) * h1[(size_t)(n - WG) * F + f];
        if (r < HG - 1) acc += di * dinv_of(r + 1, c) * h1[(size_t)(n + WG) * F + f];
        S[mm * SP + f] = acc;
    }
    __syncthreads();

    // phase 2: 64x64 GEMM tile, thread (ty,tx) computes m=ty*4..+3, f=tx*4..+3
    int ty = tid >> 4, tx = tid & 15;
    float acc[4][4] = {};
    for (int k = 0; k < 64; k += 4) {
        float4 a[4], b[4];
        #pragma unroll
        for (int i = 0; i < 4; i++) a[i] = *(const float4*)&S[(ty * 4 + i) * SP + k];
        #pragma unroll
        for (int i = 0; i < 4; i++) b[i] = *(const float4*)&BT[(tx * 4 + i) * SP + k];
        #pragma unroll
        for (int mi = 0; mi < 4; mi++)
            #pragma unroll
            for (int fi = 0; fi < 4; fi++) {
                acc[mi][fi] = fmaf(a[mi].x, b[fi].x, acc[mi][fi]);
                acc[mi][fi] = fmaf(a[mi].y, b[fi].y, acc[mi][fi]);
                acc[mi][fi] = fmaf(a[mi].z, b[fi].z, acc[mi][fi]);
                acc[mi][fi] = fmaf(a[mi].w, b[fi].w, acc[mi][fi]);
            }
    }

    // epilogue: relu + bias + partial fc dot over this thread's 4 features
    float wf[4], bb[4];
    #pragma unroll
    for (int fi = 0; fi < 4; fi++) { wf[fi] = Wfc[tx * 4 + fi]; bb[fi] = b2[tx * 4 + fi]; }
    #pragma unroll
    for (int mi = 0; mi < 4; mi++) {
        float p = 0.0f;
        #pragma unroll
        for (int fi = 0; fi < 4; fi++) p += fmaxf(acc[mi][fi] + bb[fi], 0.0f) * wf[fi];
        P[(ty * 4 + mi) * 17 + tx] = p;
    }
    __syncthreads();

    if (tid < 64) {
        float s = 0.0f;
        #pragma unroll
        for (int j = 0; j < 16; j++) s += P[tid * 17 + j];
        float z = s + bfc[0];
        out[n0 + tid] = 1.0f / (1.0f + expf(-z));
    }
}

extern "C" void kernel_launch(void* const* d_in, const int* in_sizes, int n_in,
                              void* d_out, int out_size, void* d_ws, size_t ws_size,
                              hipStream_t stream) {
    const float* x   = (const float*)d_in[0];
    // d_in[1] = edge_index (int32) — structure is a fixed 4-neighbor grid; unused.
    const float* W1  = (const float*)d_in[2];
    const float* b1  = (const float*)d_in[3];
    const float* W2  = (const float*)d_in[4];
    const float* b2  = (const float*)d_in[5];
    const float* Wfc = (const float*)d_in[6];
    const float* bfc = (const float*)d_in[7];

    float* h1  = (float*)d_ws;     // NN*64 fp32 = 64 MB scratch
    float* out = (float*)d_out;

    k1<<<(NN * F) / 256, 256, 0, stream>>>(x, W1, b1, h1);
    k2<<<NN / 64, 256, 0, stream>>>(h1, W2, b2, Wfc, bfc, out);
}

// Round 2
// 136.857 us; speedup vs baseline: 1.9414x; 1.9414x over previous
//
#include <hip/hip_runtime.h>
#include <math.h>

#define HG 512
#define WG 512
#define NN (HG * WG)
#define F 64
#define SP2 72   // LDS row stride in bf16: 144 B = 16B-aligned; b128 reads land 2-way (free)

typedef __attribute__((ext_vector_type(8))) short bf16x8;
typedef __attribute__((ext_vector_type(4))) float f32x4;

__device__ __forceinline__ float dinv_of(int r, int c) {
    float deg = 1.0f + (float)((r > 0) + (r < HG - 1) + (c > 0) + (c < WG - 1));
    return rsqrtf(deg);
}

__device__ __forceinline__ unsigned f2bf(float f) {
    unsigned u = __float_as_uint(f);
    u += 0x7fffu + ((u >> 16) & 1u);      // RTN-even
    return u >> 16;
}
__device__ __forceinline__ float bflo(unsigned u) { return __uint_as_float(u << 16); }
__device__ __forceinline__ float bfhi(unsigned u) { return __uint_as_float(u & 0xffff0000u); }

// Kernel A: h1[n][f] = relu( stencil(x)_n @ W1 + b1 ), stored bf16.
// Block = 256 threads = 256 nodes (half a grid row). Stencil computed ONCE per node.
__global__ __launch_bounds__(256) void kA(const float* __restrict__ x,
                                          const float* __restrict__ W1,
                                          const float* __restrict__ b1,
                                          unsigned short* __restrict__ h1) {
    __shared__ float2 a1s[256];
    int tid = threadIdx.x;
    int r = blockIdx.x >> 1;
    int c0 = (blockIdx.x & 1) << 8;
    int c = c0 + tid;
    int n = (r << 9) + c;
    const float2* xv = (const float2*)x;
    float di = dinv_of(r, c);
    float2 xc = xv[n];
    float s0 = di * di * xc.x, s1 = di * di * xc.y;
    if (c > 0)      { float w = di * dinv_of(r, c - 1); float2 v = xv[n - 1];   s0 += w * v.x; s1 += w * v.y; }
    if (c < WG - 1) { float w = di * dinv_of(r, c + 1); float2 v = xv[n + 1];   s0 += w * v.x; s1 += w * v.y; }
    if (r > 0)      { float w = di * dinv_of(r - 1, c); float2 v = xv[n - WG];  s0 += w * v.x; s1 += w * v.y; }
    if (r < HG - 1) { float w = di * dinv_of(r + 1, c); float2 v = xv[n + WG];  s0 += w * v.x; s1 += w * v.y; }
    a1s[tid] = make_float2(s0, s1);
    __syncthreads();

    // expand: thread covers f = 4*fq..4*fq+3 for nodes m = 16i + mg
    int fq = tid & 15, mg = tid >> 4;
    float4 w0 = ((const float4*)W1)[fq];          // W1[0][4fq..]
    float4 w1 = ((const float4*)(W1 + 64))[fq];   // W1[1][4fq..]
    float4 bb = ((const float4*)b1)[fq];
    size_t base = ((size_t)(r << 9) + c0) * F;
    #pragma unroll 4
    for (int i = 0; i < 16; i++) {
        int m = i * 16 + mg;
        float2 a = a1s[m];
        float h0 = fmaxf(fmaf(a.x, w0.x, fmaf(a.y, w1.x, bb.x)), 0.f);
        float h1v = fmaxf(fmaf(a.x, w0.y, fmaf(a.y, w1.y, bb.y)), 0.f);
        float h2 = fmaxf(fmaf(a.x, w0.z, fmaf(a.y, w1.z, bb.z)), 0.f);
        float h3 = fmaxf(fmaf(a.x, w0.w, fmaf(a.y, w1.w, bb.w)), 0.f);
        uint2 pk;
        pk.x = f2bf(h0) | (f2bf(h1v) << 16);
        pk.y = f2bf(h2) | (f2bf(h3) << 16);
        *(uint2*)(h1 + base + (size_t)m * F + fq * 4) = pk;   // 8B coalesced
    }
}

// Kernel B: per 8x32 spatial tile (256 nodes): S = stencil(h1) in LDS (bf16),
// C = S @ W2 via mfma_f32_16x16x32_bf16, fused relu+bias+fc+sigmoid epilogue.
__global__ __launch_bounds__(256) void kB(const unsigned short* __restrict__ h1,
                                          const float* __restrict__ W2,
                                          const float* __restrict__ b2,
                                          const float* __restrict__ Wfc,
                                          const float* __restrict__ bfc,
                                          float* __restrict__ out) {
    __shared__ unsigned short S[256 * SP2];   // S[m][k], m = rr*32+cc
    __shared__ unsigned short WT[64 * SP2];   // WT[n][k] = bf16(W2[k][n])
    int tid = threadIdx.x;
    int tr = blockIdx.x >> 4, tc = blockIdx.x & 15;
    int r0 = tr * 8, c0 = tc * 32;

    // stage W2 transposed as bf16 (one-time, reads coalesced)
    for (int i = tid; i < 64 * 64; i += 256) {
        int k = i >> 6, nn = i & 63;
        WT[nn * SP2 + k] = (unsigned short)f2bf(W2[i]);
    }

    // phase 1: stencil-gather S (fp32 accum of bf16 inputs)
    int fq = tid & 15, mg = tid >> 4;
    const uint2* hv = (const uint2*)h1;   // 16 x uint2 per node row
    for (int i = 0; i < 16; i++) {
        int m = i * 16 + mg;
        int rr = m >> 5, cc = m & 31;
        int rT = r0 + rr, cT = c0 + cc;
        int n = (rT << 9) + cT;
        float di = dinv_of(rT, cT);
        float a0, a1, a2, a3;
        { float w = di * di; uint2 v = hv[(size_t)n * 16 + fq];
          a0 = w * bflo(v.x); a1 = w * bfhi(v.x); a2 = w * bflo(v.y); a3 = w * bfhi(v.y); }
        if (cT > 0)      { float w = di * dinv_of(rT, cT - 1); uint2 v = hv[(size_t)(n - 1) * 16 + fq];
                           a0 += w * bflo(v.x); a1 += w * bfhi(v.x); a2 += w * bflo(v.y); a3 += w * bfhi(v.y); }
        if (cT < WG - 1) { float w = di * dinv_of(rT, cT + 1); uint2 v = hv[(size_t)(n + 1) * 16 + fq];
                           a0 += w * bflo(v.x); a1 += w * bfhi(v.x); a2 += w * bflo(v.y); a3 += w * bfhi(v.y); }
        if (rT > 0)      { float w = di * dinv_of(rT - 1, cT); uint2 v = hv[(size_t)(n - WG) * 16 + fq];
                           a0 += w * bflo(v.x); a1 += w * bfhi(v.x); a2 += w * bflo(v.y); a3 += w * bfhi(v.y); }
        if (rT < HG - 1) { float w = di * dinv_of(rT + 1, cT); uint2 v = hv[(size_t)(n + WG) * 16 + fq];
                           a0 += w * bflo(v.x); a1 += w * bfhi(v.x); a2 += w * bflo(v.y); a3 += w * bfhi(v.y); }
        uint2 pk;
        pk.x = f2bf(a0) | (f2bf(a1) << 16);
        pk.y = f2bf(a2) | (f2bf(a3) << 16);
        *(uint2*)&S[m * SP2 + fq * 4] = pk;
    }
    __syncthreads();

    // phase 2: wave wv computes rows [wv*64, wv*64+64) as 4 m-tiles of 16
    int wv = tid >> 6, lane = tid & 63;
    int q = lane >> 4, col = lane & 15;

    bf16x8 bfrag[4][2];   // [n-tile][k-half]: B[k=q*8+j][n0+col] = WT[n0+col][k]
    #pragma unroll
    for (int nt = 0; nt < 4; nt++)
        #pragma unroll
        for (int kk = 0; kk < 2; kk++)
            bfrag[nt][kk] = *(const bf16x8*)&WT[(nt * 16 + col) * SP2 + kk * 32 + q * 8];

    float b2r[4], wfr[4];
    #pragma unroll
    for (int nt = 0; nt < 4; nt++) { b2r[nt] = b2[nt * 16 + col]; wfr[nt] = Wfc[nt * 16 + col]; }
    float bfc0 = bfc[0];

    #pragma unroll
    for (int mt = 0; mt < 4; mt++) {
        int m0 = wv * 64 + mt * 16;
        // A[m=col][k=q*8+j] (+k-half offset): 16B-aligned ds_read_b128
        bf16x8 af0 = *(const bf16x8*)&S[(m0 + col) * SP2 + q * 8];
        bf16x8 af1 = *(const bf16x8*)&S[(m0 + col) * SP2 + 32 + q * 8];
        f32x4 acc[4];
        #pragma unroll
        for (int nt = 0; nt < 4; nt++) {
            f32x4 z = {0.f, 0.f, 0.f, 0.f};
            z = __builtin_amdgcn_mfma_f32_16x16x32_bf16(af0, bfrag[nt][0], z, 0, 0, 0);
            z = __builtin_amdgcn_mfma_f32_16x16x32_bf16(af1, bfrag[nt][1], z, 0, 0, 0);
            acc[nt] = z;
        }
        // epilogue: relu + b2, dot with Wfc over f (cols), reduce across 16 lanes
        float p[4] = {0.f, 0.f, 0.f, 0.f};
        #pragma unroll
        for (int nt = 0; nt < 4; nt++)
            #pragma unroll
            for (int rg = 0; rg < 4; rg++)
                p[rg] += fmaxf(acc[nt][rg] + b2r[nt], 0.f) * wfr[nt];
        #pragma unroll
        for (int rg = 0; rg < 4; rg++) {
            #pragma unroll
            for (int s = 1; s < 16; s <<= 1)
                p[rg] += __shfl_xor(p[rg], s, 64);
        }
        if (col == 0) {
            #pragma unroll
            for (int rg = 0; rg < 4; rg++) {
                int m = m0 + q * 4 + rg;                       // C/D row = q*4+reg
                int nT = (r0 + (m >> 5)) * WG + c0 + (m & 31);
                float z = p[rg] + bfc0;
                out[nT] = 1.f / (1.f + expf(-z));
            }
        }
    }
}

extern "C" void kernel_launch(void* const* d_in, const int* in_sizes, int n_in,
                              void* d_out, int out_size, void* d_ws, size_t ws_size,
                              hipStream_t stream) {
    const float* x   = (const float*)d_in[0];
    // d_in[1] = edge_index — fixed 4-neighbor grid; structure is analytic, unused.
    const float* W1  = (const float*)d_in[2];
    const float* b1  = (const float*)d_in[3];
    const float* W2  = (const float*)d_in[4];
    const float* b2  = (const float*)d_in[5];
    const float* Wfc = (const float*)d_in[6];
    const float* bfc = (const float*)d_in[7];

    unsigned short* h1 = (unsigned short*)d_ws;   // NN*64 bf16 = 32 MB scratch
    float* out = (float*)d_out;

    kA<<<NN / 256, 256, 0, stream>>>(x, W1, b1, h1);
    kB<<<NN / 256, 256, 0, stream>>>(h1, W2, b2, Wfc, bfc, out);
}

// Round 3
// 95.179 us; speedup vs baseline: 2.7916x; 1.4379x over previous
//
#include <hip/hip_runtime.h>
#include <math.h>

#define HG 512
#define WG 512
#define F 64
#define TS 16          // output tile side
#define HS 18          // halo'd tile side (h1 region)
#define HN (HS * HS)   // 324 halo nodes
#define SP 72          // Hs/WT row stride in bf16: 144 B, 16B-aligned

typedef __attribute__((ext_vector_type(8))) short bf16x8;
typedef __attribute__((ext_vector_type(4))) float f32x4;

__device__ __forceinline__ unsigned f2bf(float f) {
    unsigned u = __float_as_uint(f);
    u += 0x7fffu + ((u >> 16) & 1u);      // RTN-even
    return u >> 16;
}
__device__ __forceinline__ float bflo(unsigned u) { return __uint_as_float(u << 16); }
__device__ __forceinline__ float bfhi(unsigned u) { return __uint_as_float(u & 0xffff0000u); }

__device__ __forceinline__ float dinv_of(int r, int c) {
    // deg = 1 + #neighbors ∈ {3,4,5}; correctly-rounded fp32 rsqrt constants
    int nb = (r > 0) + (r < HG - 1) + (c > 0) + (c < WG - 1);
    return nb == 4 ? 0.4472135954999579f : (nb == 3 ? 0.5f : 0.5773502691896258f);
}

// Fully fused: x -> stencil1 -> W1/relu (h1 bf16 in LDS, halo'd tile) ->
// stencil2 (reg A-frags) -> MFMA W2 -> relu/b2 -> Wfc -> sigmoid -> out.
// h1 never touches HBM.
__global__ __launch_bounds__(256) void fused(const float* __restrict__ x,
                                             const float* __restrict__ W1,
                                             const float* __restrict__ b1,
                                             const float* __restrict__ W2,
                                             const float* __restrict__ b2,
                                             const float* __restrict__ Wfc,
                                             const float* __restrict__ bfc,
                                             float* __restrict__ out) {
    __shared__ unsigned short Hs[HN * SP];   // h1 bf16, row = lr*18+lc
    __shared__ unsigned short WT[64 * SP];   // WT[n][k] = bf16(W2[k][n])
    __shared__ float2 a1s[HN];               // stencil1 results

    int tid = threadIdx.x;
    int tr = blockIdx.x >> 5, tc = blockIdx.x & 31;   // 32x32 tiles
    int r0 = tr * TS, c0 = tc * TS;

    // stage W2^T as bf16 (reads coalesced)
    for (int i = tid; i < 64 * 64; i += 256) {
        int k = i >> 6, n = i & 63;
        WT[n * SP + k] = (unsigned short)f2bf(W2[i]);
    }

    // ---- phase 0: stencil1 over the 18x18 halo region (from global x) ----
    const float2* xv = (const float2*)x;
    for (int node = tid; node < HN; node += 256) {
        int lr = (node * 57) >> 10;          // node / 18, exact for node < 324
        int lc = node - lr * 18;
        int rT = r0 - 1 + lr, cT = c0 - 1 + lc;
        float s0 = 0.f, s1 = 0.f;            // out-of-grid rows -> finite zeros
        if (rT >= 0 && rT < HG && cT >= 0 && cT < WG) {
            int n = (rT << 9) + cT;
            float di = dinv_of(rT, cT);
            float2 v = xv[n];
            s0 = di * di * v.x; s1 = di * di * v.y;
            if (cT > 0)      { float w = di * dinv_of(rT, cT - 1); float2 t = xv[n - 1];  s0 += w * t.x; s1 += w * t.y; }
            if (cT < WG - 1) { float w = di * dinv_of(rT, cT + 1); float2 t = xv[n + 1];  s0 += w * t.x; s1 += w * t.y; }
            if (rT > 0)      { float w = di * dinv_of(rT - 1, cT); float2 t = xv[n - WG]; s0 += w * t.x; s1 += w * t.y; }
            if (rT < HG - 1) { float w = di * dinv_of(rT + 1, cT); float2 t = xv[n + WG]; s0 += w * t.x; s1 += w * t.y; }
        }
        a1s[node] = make_float2(s0, s1);
    }

    // ---- phase 1: expand a1 -> h1 bf16 in LDS (thread = (node stripe, f-quad)) ----
    int fq = tid & 15;
    float4 w0 = ((const float4*)W1)[fq];          // W1[0][4fq..]
    float4 w1 = ((const float4*)(W1 + 64))[fq];   // W1[1][4fq..]
    float4 bb = ((const float4*)b1)[fq];
    __syncthreads();
    for (int node = (tid >> 4); node < HN; node += 16) {
        float2 a = a1s[node];
        float h0 = fmaxf(fmaf(a.x, w0.x, fmaf(a.y, w1.x, bb.x)), 0.f);
        float h1v = fmaxf(fmaf(a.x, w0.y, fmaf(a.y, w1.y, bb.y)), 0.f);
        float h2 = fmaxf(fmaf(a.x, w0.z, fmaf(a.y, w1.z, bb.z)), 0.f);
        float h3 = fmaxf(fmaf(a.x, w0.w, fmaf(a.y, w1.w, bb.w)), 0.f);
        uint2 pk;
        pk.x = f2bf(h0) | (f2bf(h1v) << 16);
        pk.y = f2bf(h2) | (f2bf(h3) << 16);
        *(uint2*)&Hs[node * SP + fq * 4] = pk;
    }
    __syncthreads();

    // ---- phase 2: stencil2 -> A-frags in regs; MFMA vs W2^T; fused epilogue ----
    int wv = tid >> 6, lane = tid & 63;
    int q = lane >> 4, col = lane & 15;

    bf16x8 bfrag[4][2];   // B[k=q*8+j][n=nt*16+col] = WT[n][k]
    #pragma unroll
    for (int nt = 0; nt < 4; nt++)
        #pragma unroll
        for (int kk = 0; kk < 2; kk++)
            bfrag[nt][kk] = *(const bf16x8*)&WT[(nt * 16 + col) * SP + kk * 32 + q * 8];

    float b2r[4], wfr[4];
    #pragma unroll
    for (int nt = 0; nt < 4; nt++) { b2r[nt] = b2[nt * 16 + col]; wfr[nt] = Wfc[nt * 16 + col]; }
    float bfc0 = bfc[0];

    #pragma unroll
    for (int mt = 0; mt < 4; mt++) {
        // A-row m = wv*64 + mt*16 + col  ->  tile coords (wv*4+mt, col)
        int lr = wv * 4 + mt + 1, lc = col + 1;
        int rT = r0 + lr - 1, cT = c0 + lc - 1;
        float di = dinv_of(rT, cT);
        float wc = di * di;
        float wl = (cT > 0)      ? di * dinv_of(rT, cT - 1) : 0.f;
        float wr = (cT < WG - 1) ? di * dinv_of(rT, cT + 1) : 0.f;
        float wu = (rT > 0)      ? di * dinv_of(rT - 1, cT) : 0.f;
        float wd = (rT < HG - 1) ? di * dinv_of(rT + 1, cT) : 0.f;
        const unsigned short* hp = &Hs[(lr * HS + lc) * SP];

        bf16x8 af[2];
        #pragma unroll
        for (int ck = 0; ck < 2; ck++) {
            int off = ck * 32 + q * 8;      // A[m=col][k=q*8+j] (+32 for 2nd half)
            uint4 vc = *(const uint4*)(hp + off);
            uint4 vl = *(const uint4*)(hp - SP + off);
            uint4 vr = *(const uint4*)(hp + SP + off);
            uint4 vu = *(const uint4*)(hp - HS * SP + off);
            uint4 vd = *(const uint4*)(hp + HS * SP + off);
            const unsigned *ac = (const unsigned*)&vc, *al = (const unsigned*)&vl,
                           *ar = (const unsigned*)&vr, *au = (const unsigned*)&vu,
                           *ad = (const unsigned*)&vd;
            unsigned pk[4];
            #pragma unroll
            for (int u = 0; u < 4; u++) {
                float lo = wc * bflo(ac[u]) + wl * bflo(al[u]) + wr * bflo(ar[u])
                         + wu * bflo(au[u]) + wd * bflo(ad[u]);
                float hi = wc * bfhi(ac[u]) + wl * bfhi(al[u]) + wr * bfhi(ar[u])
                         + wu * bfhi(au[u]) + wd * bfhi(ad[u]);
                pk[u] = f2bf(lo) | (f2bf(hi) << 16);
            }
            af[ck] = *(bf16x8*)pk;
        }

        float p[4] = {0.f, 0.f, 0.f, 0.f};
        #pragma unroll
        for (int nt = 0; nt < 4; nt++) {
            f32x4 z = {0.f, 0.f, 0.f, 0.f};
            z = __builtin_amdgcn_mfma_f32_16x16x32_bf16(af[0], bfrag[nt][0], z, 0, 0, 0);
            z = __builtin_amdgcn_mfma_f32_16x16x32_bf16(af[1], bfrag[nt][1], z, 0, 0, 0);
            #pragma unroll
            for (int rg = 0; rg < 4; rg++)
                p[rg] += fmaxf(z[rg] + b2r[nt], 0.f) * wfr[nt];
        }
        #pragma unroll
        for (int rg = 0; rg < 4; rg++) {
            #pragma unroll
            for (int s = 1; s < 16; s <<= 1)
                p[rg] += __shfl_xor(p[rg], s, 64);
        }
        if (col == 0) {
            #pragma unroll
            for (int rg = 0; rg < 4; rg++) {
                // C/D row = q*4+rg -> tile row wv*4+mt, tile col q*4+rg
                int nT = (r0 + wv * 4 + mt) * WG + c0 + q * 4 + rg;
                float zz = p[rg] + bfc0;
                out[nT] = 1.f / (1.f + expf(-zz));
            }
        }
    }
}

extern "C" void kernel_launch(void* const* d_in, const int* in_sizes, int n_in,
                              void* d_out, int out_size, void* d_ws, size_t ws_size,
                              hipStream_t stream) {
    const float* x   = (const float*)d_in[0];
    // d_in[1] = edge_index — fixed 4-neighbor grid; structure analytic, unused.
    const float* W1  = (const float*)d_in[2];
    const float* b1  = (const float*)d_in[3];
    const float* W2  = (const float*)d_in[4];
    const float* b2  = (const float*)d_in[5];
    const float* Wfc = (const float*)d_in[6];
    const float* bfc = (const float*)d_in[7];
    float* out = (float*)d_out;

    fused<<<(HG / TS) * (WG / TS), 256, 0, stream>>>(x, W1, b1, W2, b2, Wfc, bfc, out);
}

// Round 5
// 90.445 us; speedup vs baseline: 2.9377x; 1.0523x over previous
//
#include <hip/hip_runtime.h>
#include <math.h>

#define HG 512
#define WG 512
#define F 64
#define TS 16          // output tile side
#define HS 18          // halo'd tile side
#define HN (HS * HS)   // 324 halo nodes

typedef _Float16 f16x8 __attribute__((ext_vector_type(8)));
typedef __fp16 fp16x2 __attribute__((ext_vector_type(2)));
typedef __attribute__((ext_vector_type(4))) float f32x4;

__device__ __forceinline__ float dinv_of(int r, int c) {
    int nb = (r > 0) + (r < HG - 1) + (c > 0) + (c < WG - 1);
    return nb == 4 ? 0.4472135954999579f : (nb == 3 ? 0.5f : 0.5773502691896258f);
}

// Byte offset of 16B chunk `ch` (0..7) in swizzled 128B row `row`.
// Key (row ^ row>>3)&7 keeps BOTH the phase-1 strided writes and the
// phase-2 quad reads at <=2-way bank aliasing (free) with zero padding.
__device__ __forceinline__ int swz(int row, int ch) {
    int key = (row ^ (row >> 3)) & 7;
    return row * 128 + ((ch ^ key) << 4);
}

// Fully fused GCN: x -> stencil1 -> W1/relu (h1 f16 tile in LDS, 18x18 halo) ->
// stencil2 via v_pk_fma_f16 directly into MFMA A-frags -> mfma f16 x W2 ->
// relu/b2 -> Wfc dot -> sigmoid -> out. h1 never touches HBM.
__global__ __launch_bounds__(256) void fused(const float* __restrict__ x,
                                             const float* __restrict__ W1,
                                             const float* __restrict__ b1,
                                             const float* __restrict__ W2,
                                             const float* __restrict__ b2,
                                             const float* __restrict__ Wfc,
                                             const float* __restrict__ bfc,
                                             float* __restrict__ out) {
    __shared__ unsigned short Hs[HN * 64];   // 41472 B: h1 f16, swizzled rows
    __shared__ unsigned short WT[64 * 64];   // 8192 B: W2^T f16, swizzled rows
    __shared__ float2 a1s[HN];               // 2592 B: stencil1 results
    // total 52256 B -> 3 blocks/CU

    char* hb = (char*)Hs;
    char* wb = (char*)WT;
    int tid = threadIdx.x;
    int tr = blockIdx.x >> 5, tc = blockIdx.x & 31;   // 32x32 tiles
    int r0 = tr * TS, c0 = tc * TS;

    // stage W2 -> f16, transposed + swizzled: WT[n][k] = f16(W2[k][n])
    for (int i = tid; i < 64 * 64; i += 256) {
        int k = i >> 6, n = i & 63;
        *(_Float16*)(wb + swz(n, k >> 3) + (k & 7) * 2) = (_Float16)W2[i];
    }

    // ---- phase 0: stencil1 over the 18x18 halo region (global x) ----
    const float2* xv = (const float2*)x;
    for (int node = tid; node < HN; node += 256) {
        int lr = (node * 57) >> 10;          // node / 18, exact for node < 324
        int lc = node - lr * 18;
        int rT = r0 - 1 + lr, cT = c0 - 1 + lc;
        float s0 = 0.f, s1 = 0.f;            // out-of-grid -> zeros (weighted 0 later)
        if (rT >= 0 && rT < HG && cT >= 0 && cT < WG) {
            int n = (rT << 9) + cT;
            float di = dinv_of(rT, cT);
            float2 v = xv[n];
            s0 = di * di * v.x; s1 = di * di * v.y;
            if (cT > 0)      { float w = di * dinv_of(rT, cT - 1); float2 t = xv[n - 1];  s0 += w * t.x; s1 += w * t.y; }
            if (cT < WG - 1) { float w = di * dinv_of(rT, cT + 1); float2 t = xv[n + 1];  s0 += w * t.x; s1 += w * t.y; }
            if (rT > 0)      { float w = di * dinv_of(rT - 1, cT); float2 t = xv[n - WG]; s0 += w * t.x; s1 += w * t.y; }
            if (rT < HG - 1) { float w = di * dinv_of(rT + 1, cT); float2 t = xv[n + WG]; s0 += w * t.x; s1 += w * t.y; }
        }
        a1s[node] = make_float2(s0, s1);
    }

    // ---- phase 1: expand a1 -> h1 f16 in LDS ----
    int fq = tid & 15;
    float4 w0 = ((const float4*)W1)[fq];          // W1[0][4fq..]
    float4 w1 = ((const float4*)(W1 + 64))[fq];   // W1[1][4fq..]
    float4 bb = ((const float4*)b1)[fq];
    __syncthreads();
    for (int node = (tid >> 4); node < HN; node += 16) {
        float2 a = a1s[node];
        float h0 = fmaxf(fmaf(a.x, w0.x, fmaf(a.y, w1.x, bb.x)), 0.f);
        float h1v = fmaxf(fmaf(a.x, w0.y, fmaf(a.y, w1.y, bb.y)), 0.f);
        float h2 = fmaxf(fmaf(a.x, w0.z, fmaf(a.y, w1.z, bb.z)), 0.f);
        float h3 = fmaxf(fmaf(a.x, w0.w, fmaf(a.y, w1.w, bb.w)), 0.f);
        fp16x2 p0 = __builtin_amdgcn_cvt_pkrtz(h0, h1v);
        fp16x2 p1 = __builtin_amdgcn_cvt_pkrtz(h2, h3);
        uint2 pk;
        pk.x = __builtin_bit_cast(unsigned, p0);
        pk.y = __builtin_bit_cast(unsigned, p1);
        *(uint2*)(hb + swz(node, fq >> 1) + (fq & 1) * 8) = pk;
    }
    __syncthreads();

    // ---- phase 2: stencil2 (pk_fma) -> A-frags; MFMA vs W2^T; fused epilogue ----
    int wv = tid >> 6, lane = tid & 63;
    int q = lane >> 4, col = lane & 15;

    f16x8 bfrag[4][2];   // B[k=ck*32+q*8+j][n=nt*16+col] = WT[n][k]
    #pragma unroll
    for (int nt = 0; nt < 4; nt++)
        #pragma unroll
        for (int ck = 0; ck < 2; ck++)
            bfrag[nt][ck] = *(const f16x8*)(wb + swz(nt * 16 + col, ck * 4 + q));

    float b2r[4], wfr[4];
    #pragma unroll
    for (int nt = 0; nt < 4; nt++) { b2r[nt] = b2[nt * 16 + col]; wfr[nt] = Wfc[nt * 16 + col]; }
    float bfc0 = bfc[0];

    #pragma unroll
    for (int mt = 0; mt < 4; mt++) {
        // A-row m=col -> node (tile row wv*4+mt, tile col `col`)
        int lr = wv * 4 + mt + 1, lc = col + 1;
        int rT = r0 + lr - 1, cT = c0 + lc - 1;
        float di = dinv_of(rT, cT);
        _Float16 hc = (_Float16)(di * di);
        _Float16 hl = (_Float16)((cT > 0)      ? di * dinv_of(rT, cT - 1) : 0.f);
        _Float16 hr = (_Float16)((cT < WG - 1) ? di * dinv_of(rT, cT + 1) : 0.f);
        _Float16 hu = (_Float16)((rT > 0)      ? di * dinv_of(rT - 1, cT) : 0.f);
        _Float16 hd = (_Float16)((rT < HG - 1) ? di * dinv_of(rT + 1, cT) : 0.f);
        f16x8 wc8 = {hc, hc, hc, hc, hc, hc, hc, hc};
        f16x8 wl8 = {hl, hl, hl, hl, hl, hl, hl, hl};
        f16x8 wr8 = {hr, hr, hr, hr, hr, hr, hr, hr};
        f16x8 wu8 = {hu, hu, hu, hu, hu, hu, hu, hu};
        f16x8 wd8 = {hd, hd, hd, hd, hd, hd, hd, hd};
        int hrow = lr * HS + lc;

        f16x8 af[2];
        #pragma unroll
        for (int ck = 0; ck < 2; ck++) {
            int c = ck * 4 + q;              // A[m=col][k=ck*32+q*8+j]
            f16x8 vc = *(const f16x8*)(hb + swz(hrow, c));
            f16x8 vl = *(const f16x8*)(hb + swz(hrow - 1, c));
            f16x8 vr = *(const f16x8*)(hb + swz(hrow + 1, c));
            f16x8 vu = *(const f16x8*)(hb + swz(hrow - HS, c));
            f16x8 vd = *(const f16x8*)(hb + swz(hrow + HS, c));
            f16x8 a = vc * wc8;
            a += vl * wl8;
            a += vr * wr8;
            a += vu * wu8;
            a += vd * wd8;
            af[ck] = a;
        }

        float p[4] = {0.f, 0.f, 0.f, 0.f};
        #pragma unroll
        for (int nt = 0; nt < 4; nt++) {
            f32x4 z = {0.f, 0.f, 0.f, 0.f};
            z = __builtin_amdgcn_mfma_f32_16x16x32_f16(af[0], bfrag[nt][0], z, 0, 0, 0);
            z = __builtin_amdgcn_mfma_f32_16x16x32_f16(af[1], bfrag[nt][1], z, 0, 0, 0);
            #pragma unroll
            for (int rg = 0; rg < 4; rg++)
                p[rg] += fmaxf(z[rg] + b2r[nt], 0.f) * wfr[nt];
        }
        #pragma unroll
        for (int rg = 0; rg < 4; rg++) {
            #pragma unroll
            for (int s = 1; s < 16; s <<= 1)
                p[rg] += __shfl_xor(p[rg], s, 64);
        }
        if (col == 0) {
            #pragma unroll
            for (int rg = 0; rg < 4; rg++) {
                // C/D row q*4+rg = M index -> tile col; tile row = wv*4+mt
                int nT = (r0 + wv * 4 + mt) * WG + c0 + q * 4 + rg;
                float zz = p[rg] + bfc0;
                out[nT] = 1.f / (1.f + expf(-zz));
            }
        }
    }
}

extern "C" void kernel_launch(void* const* d_in, const int* in_sizes, int n_in,
                              void* d_out, int out_size, void* d_ws, size_t ws_size,
                              hipStream_t stream) {
    const float* x   = (const float*)d_in[0];
    // d_in[1] = edge_index — fixed 4-neighbor grid; structure analytic, unused.
    const float* W1  = (const float*)d_in[2];
    const float* b1  = (const float*)d_in[3];
    const float* W2  = (const float*)d_in[4];
    const float* b2  = (const float*)d_in[5];
    const float* Wfc = (const float*)d_in[6];
    const float* bfc = (const float*)d_in[7];
    float* out = (float*)d_out;

    fused<<<(HG / TS) * (WG / TS), 256, 0, stream>>>(x, W1, b1, W2, b2, Wfc, bfc, out);
}

// Round 6
// 86.657 us; speedup vs baseline: 3.0661x; 1.0437x over previous
//
#include <hip/hip_runtime.h>
#include <hip/hip_fp16.h>
#include <math.h>

#define HG 512
#define WG 512
#define F 64
#define TS 16          // output tile side
#define HS 18          // halo'd tile side
#define HN (HS * HS)   // 324 halo nodes

typedef _Float16 f16x8 __attribute__((ext_vector_type(8)));
typedef __fp16 fp16x2 __attribute__((ext_vector_type(2)));
typedef __attribute__((ext_vector_type(4))) float f32x4;

__device__ __forceinline__ float dinv_of(int r, int c) {
    int nb = (r > 0) + (r < HG - 1) + (c > 0) + (c < WG - 1);
    return nb == 4 ? 0.4472135954999579f : (nb == 3 ? 0.5f : 0.5773502691896258f);
}

// Byte offset of 16B chunk `ch` (0..7) in swizzled 128B row `row`.
__device__ __forceinline__ int swz(int row, int ch) {
    int key = (row ^ (row >> 3)) & 7;
    return row * 128 + ((ch ^ key) << 4);
}

__device__ __forceinline__ __half2 bch2(unsigned u) { return __builtin_bit_cast(__half2, u); }

// Fully fused GCN, 1024-thread blocks for 32 waves/CU.
__global__ __launch_bounds__(1024, 8) void fused(const float* __restrict__ x,
                                                 const float* __restrict__ W1,
                                                 const float* __restrict__ b1,
                                                 const float* __restrict__ W2,
                                                 const float* __restrict__ b2,
                                                 const float* __restrict__ Wfc,
                                                 const float* __restrict__ bfc,
                                                 float* __restrict__ out) {
    __shared__ unsigned short Hs[HN * 64];   // 41472 B: h1 f16, swizzled rows
    __shared__ unsigned short WT[64 * 64];   // 8192 B: W2^T f16, swizzled rows
    __shared__ float2 a1s[HN];               // 2592 B: stencil1 results
    // total 52256 B -> 2 blocks/CU (wave-cap), 32 waves/CU

    char* hb = (char*)Hs;
    char* wb = (char*)WT;
    int tid = threadIdx.x;
    int tr = blockIdx.x >> 5, tc = blockIdx.x & 31;   // 32x32 tiles
    int r0 = tr * TS, c0 = tc * TS;

    // stage W2 -> f16, transposed + swizzled: WT[n][k] = f16(W2[k][n])
    for (int i = tid; i < 64 * 64; i += 1024) {
        int k = i >> 6, n = i & 63;
        *(_Float16*)(wb + swz(n, k >> 3) + (k & 7) * 2) = (_Float16)W2[i];
    }

    // ---- phase 0: stencil1 over the 18x18 halo region (global x) ----
    const float2* xv = (const float2*)x;
    if (tid < HN) {
        int node = tid;
        int lr = (node * 57) >> 10;          // node / 18, exact for node < 324
        int lc = node - lr * 18;
        int rT = r0 - 1 + lr, cT = c0 - 1 + lc;
        float s0 = 0.f, s1 = 0.f;            // out-of-grid -> zeros
        if (rT >= 0 && rT < HG && cT >= 0 && cT < WG) {
            int n = (rT << 9) + cT;
            float di = dinv_of(rT, cT);
            float2 v = xv[n];
            s0 = di * di * v.x; s1 = di * di * v.y;
            if (cT > 0)      { float w = di * dinv_of(rT, cT - 1); float2 t = xv[n - 1];  s0 += w * t.x; s1 += w * t.y; }
            if (cT < WG - 1) { float w = di * dinv_of(rT, cT + 1); float2 t = xv[n + 1];  s0 += w * t.x; s1 += w * t.y; }
            if (rT > 0)      { float w = di * dinv_of(rT - 1, cT); float2 t = xv[n - WG]; s0 += w * t.x; s1 += w * t.y; }
            if (rT < HG - 1) { float w = di * dinv_of(rT + 1, cT); float2 t = xv[n + WG]; s0 += w * t.x; s1 += w * t.y; }
        }
        a1s[node] = make_float2(s0, s1);
    }

    // ---- phase 1: expand a1 -> h1 f16 in LDS ----
    int fq = tid & 15;
    float4 w0 = ((const float4*)W1)[fq];          // W1[0][4fq..]
    float4 w1 = ((const float4*)(W1 + 64))[fq];   // W1[1][4fq..]
    float4 bb = ((const float4*)b1)[fq];
    __syncthreads();
    for (int node = (tid >> 4); node < HN; node += 64) {
        float2 a = a1s[node];
        float h0 = fmaxf(fmaf(a.x, w0.x, fmaf(a.y, w1.x, bb.x)), 0.f);
        float h1v = fmaxf(fmaf(a.x, w0.y, fmaf(a.y, w1.y, bb.y)), 0.f);
        float h2 = fmaxf(fmaf(a.x, w0.z, fmaf(a.y, w1.z, bb.z)), 0.f);
        float h3 = fmaxf(fmaf(a.x, w0.w, fmaf(a.y, w1.w, bb.w)), 0.f);
        fp16x2 p0 = __builtin_amdgcn_cvt_pkrtz(h0, h1v);
        fp16x2 p1 = __builtin_amdgcn_cvt_pkrtz(h2, h3);
        uint2 pk;
        pk.x = __builtin_bit_cast(unsigned, p0);
        pk.y = __builtin_bit_cast(unsigned, p1);
        *(uint2*)(hb + swz(node, fq >> 1) + (fq & 1) * 8) = pk;
    }
    __syncthreads();

    // ---- phase 2: wave wv handles m-tile mt = wv (16 waves = 16 m-tiles) ----
    int wv = tid >> 6, lane = tid & 63;
    int q = lane >> 4, col = lane & 15;

    // node for A-row m=col: tile row wv, tile col `col`
    int lr = wv + 1, lc = col + 1;
    int rT = r0 + wv, cT = c0 + col;
    float di = dinv_of(rT, cT);
    __half2 wc2 = __half2half2(__float2half(di * di));
    __half2 wl2 = __half2half2(__float2half((cT > 0)      ? di * dinv_of(rT, cT - 1) : 0.f));
    __half2 wr2 = __half2half2(__float2half((cT < WG - 1) ? di * dinv_of(rT, cT + 1) : 0.f));
    __half2 wu2 = __half2half2(__float2half((rT > 0)      ? di * dinv_of(rT - 1, cT) : 0.f));
    __half2 wd2 = __half2half2(__float2half((rT < HG - 1) ? di * dinv_of(rT + 1, cT) : 0.f));
    int hrow = lr * HS + lc;

    f16x8 af[2];
    #pragma unroll
    for (int ck = 0; ck < 2; ck++) {
        int c = ck * 4 + q;              // A[m=col][k=ck*32+q*8+j]
        uint4 vc = *(const uint4*)(hb + swz(hrow, c));
        uint4 vl = *(const uint4*)(hb + swz(hrow - 1, c));
        uint4 vr = *(const uint4*)(hb + swz(hrow + 1, c));
        uint4 vu = *(const uint4*)(hb + swz(hrow - HS, c));
        uint4 vd = *(const uint4*)(hb + swz(hrow + HS, c));
        const unsigned* pc = (const unsigned*)&vc;
        const unsigned* pl = (const unsigned*)&vl;
        const unsigned* pr = (const unsigned*)&vr;
        const unsigned* pu = (const unsigned*)&vu;
        const unsigned* pd = (const unsigned*)&vd;
        unsigned res[4];
        #pragma unroll
        for (int u = 0; u < 4; u++) {
            __half2 a = __hmul2(bch2(pc[u]), wc2);
            a = __hfma2(bch2(pl[u]), wl2, a);
            a = __hfma2(bch2(pr[u]), wr2, a);
            a = __hfma2(bch2(pu[u]), wu2, a);
            a = __hfma2(bch2(pd[u]), wd2, a);
            res[u] = __builtin_bit_cast(unsigned, a);
        }
        uint4 r4 = {res[0], res[1], res[2], res[3]};
        af[ck] = __builtin_bit_cast(f16x8, r4);
    }

    float p[4] = {0.f, 0.f, 0.f, 0.f};
    #pragma unroll
    for (int nt = 0; nt < 4; nt++) {
        // B frags loaded per-nt (keeps VGPRs <= 64)
        f16x8 bf0 = *(const f16x8*)(wb + swz(nt * 16 + col, q));
        f16x8 bf1 = *(const f16x8*)(wb + swz(nt * 16 + col, 4 + q));
        f32x4 z = {0.f, 0.f, 0.f, 0.f};
        z = __builtin_amdgcn_mfma_f32_16x16x32_f16(af[0], bf0, z, 0, 0, 0);
        z = __builtin_amdgcn_mfma_f32_16x16x32_f16(af[1], bf1, z, 0, 0, 0);
        float b2v = b2[nt * 16 + col];
        float wfv = Wfc[nt * 16 + col];
        #pragma unroll
        for (int rg = 0; rg < 4; rg++)
            p[rg] += fmaxf(z[rg] + b2v, 0.f) * wfv;
    }
    #pragma unroll
    for (int rg = 0; rg < 4; rg++) {
        #pragma unroll
        for (int s = 1; s < 16; s <<= 1)
            p[rg] += __shfl_xor(p[rg], s, 64);
    }
    if (col == 0) {
        float bfc0 = bfc[0];
        #pragma unroll
        for (int rg = 0; rg < 4; rg++) {
            // C/D row q*4+rg -> tile col; tile row = wv
            int nT = (r0 + wv) * WG + c0 + q * 4 + rg;
            float zz = p[rg] + bfc0;
            out[nT] = 1.f / (1.f + expf(-zz));
        }
    }
}

extern "C" void kernel_launch(void* const* d_in, const int* in_sizes, int n_in,
                              void* d_out, int out_size, void* d_ws, size_t ws_size,
                              hipStream_t stream) {
    const float* x   = (const float*)d_in[0];
    // d_in[1] = edge_index — fixed 4-neighbor grid; structure analytic, unused.
    const float* W1  = (const float*)d_in[2];
    const float* b1  = (const float*)d_in[3];
    const float* W2  = (const float*)d_in[4];
    const float* b2  = (const float*)d_in[5];
    const float* Wfc = (const float*)d_in[6];
    const float* bfc = (const float*)d_in[7];
    float* out = (float*)d_out;

    fused<<<(HG / TS) * (WG / TS), 1024, 0, stream>>>(x, W1, b1, W2, b2, Wfc, bfc, out);
}